// Round 8
// 1238.638 us; speedup vs baseline: 1.0442x; 1.0442x over previous
//
#include <hip/hip_runtime.h>
#include <math.h>

#define FDIM 128
#define NEG_SLOPE 0.2f
#define LN_EPS 1e-5f

// ---------------- CSR build ----------------

__global__ void k_zero(int* __restrict__ p, int n) {
    int i = blockIdx.x * blockDim.x + threadIdx.x;
    if (i < n) p[i] = 0;
}

__global__ void k_deg(const int* __restrict__ ei, int E, int* __restrict__ deg) {
    int i = blockIdx.x * blockDim.x + threadIdx.x;
    if (i < E) atomicAdd(&deg[ei[E + i]], 1);
}

// single-block exclusive scan over N elements (N ~ 100k), 1024 threads
__global__ __launch_bounds__(1024) void k_scan(const int* __restrict__ deg,
                                               int* __restrict__ offs, int N) {
    __shared__ int tl[1024];
    int tid = threadIdx.x;
    int chunk = (N + 1023) >> 10;
    int s = tid * chunk;
    int e = s + chunk; if (e > N) e = N;
    int sum = 0;
    for (int i = s; i < e; ++i) sum += deg[i];
    tl[tid] = sum;
    __syncthreads();
    for (int off = 1; off < 1024; off <<= 1) {
        int v = (tid >= off) ? tl[tid - off] : 0;
        __syncthreads();
        tl[tid] += v;
        __syncthreads();
    }
    int run = tl[tid] - sum;  // exclusive prefix for this thread's chunk
    for (int i = s; i < e; ++i) { offs[i] = run; run += deg[i]; }
    if (tid == 1023) offs[N] = run;  // == E
}

__global__ void k_fill(const int* __restrict__ ei, int E, const int* __restrict__ offs,
                       int* __restrict__ cur, int* __restrict__ csr_src) {
    int i = blockIdx.x * blockDim.x + threadIdx.x;
    if (i < E) {
        int dst = ei[E + i];
        int p = offs[dst] + atomicAdd(&cur[dst], 1);
        csr_src[p] = ei[i];
    }
}

// ---------------- xl / xr linear transforms (baseline, known-good) ----------------
__global__ __launch_bounds__(256) void k_xlxr(const float* __restrict__ x,
        const float* __restrict__ Wl, const float* __restrict__ bl,
        const float* __restrict__ Wr, const float* __restrict__ br,
        float* __restrict__ xl, float* __restrict__ xr, int N) {
    __shared__ __align__(16) float xs[32][128];
    int tid = threadIdx.x;
    int row0 = blockIdx.x * 32;
    for (int v = tid; v < 32 * 32; v += 256) {   // 1024 float4
        int r = v >> 5, c4 = v & 31;
        int gr = row0 + r;
        float4 val = (gr < N) ? ((const float4*)x)[(size_t)gr * 32 + c4]
                              : make_float4(0.f, 0.f, 0.f, 0.f);
        *(float4*)&xs[r][c4 * 4] = val;
    }
    __syncthreads();

    int cg = tid & 63;   // 64 col groups of 4 -> 256 cols
    int rg = tid >> 6;   // 4 row groups of 8
    int j = cg * 4;
    const float* W = (j < 128) ? (Wl + j) : (Wr + (j - 128));
    const float* bp = (j < 128) ? (bl + j) : (br + (j - 128));
    float4 acc[8];
#pragma unroll
    for (int r = 0; r < 8; ++r) acc[r] = make_float4(0.f, 0.f, 0.f, 0.f);

    for (int k = 0; k < 128; ++k) {
        float4 w = *(const float4*)(W + (size_t)k * 128);
#pragma unroll
        for (int r = 0; r < 8; ++r) {
            float s = xs[rg * 8 + r][k];  // wave-uniform -> LDS broadcast
            acc[r].x += s * w.x; acc[r].y += s * w.y;
            acc[r].z += s * w.z; acc[r].w += s * w.w;
        }
    }
    float4 b = *(const float4*)bp;
    float* outb = (j < 128) ? xl : xr;
    int jj = (j < 128) ? j : (j - 128);
#pragma unroll
    for (int r = 0; r < 8; ++r) {
        int gr = row0 + rg * 8 + r;
        if (gr < N) {
            float4 v = make_float4(acc[r].x + b.x, acc[r].y + b.y,
                                   acc[r].z + b.z, acc[r].w + b.w);
            *(float4*)&outb[(size_t)gr * 128 + jj] = v;
        }
    }
}

// ---------------- GATv2 aggregation: one wave per node, online softmax ----------
// Optimized vs baseline: two independent online-softmax chains over even/odd
// edges (merged exactly at the end) + paired load issue for 2x memory-level
// parallelism. Arithmetic identical up to associative softmax reordering.
__global__ __launch_bounds__(256) void k_gat(const float* __restrict__ xl,
        const float* __restrict__ xr, const float* __restrict__ att,
        const float* __restrict__ bias,
        const int* __restrict__ offs, const int* __restrict__ csr_src,
        float* __restrict__ h, int N) {
    int wave = threadIdx.x >> 6;
    int lane = threadIdx.x & 63;
    int node = blockIdx.x * 4 + wave;
    if (node >= N) return;

    int c0 = lane * 2;  // channel pair; head = c0>>4, 8 lanes per head
    float2 xrv = *(const float2*)&xr[(size_t)node * 128 + c0];
    float2 av  = *(const float2*)&att[c0];

    float mA = -3.0e38f, lA = 0.f;
    float mB = -3.0e38f, lB = 0.f;
    float2 aA = make_float2(0.f, 0.f);
    float2 aB = make_float2(0.f, 0.f);

    int e0 = offs[node], e1 = offs[node + 1];
    for (int i = e0; i < e1; i += 2) {
        // issue both edge loads up-front (independent; wave-uniform branch)
        bool has2 = (i + 1) < e1;
        int s0 = csr_src[i];
        int s1 = has2 ? csr_src[i + 1] : s0;
        float2 x0 = *(const float2*)&xl[(size_t)s0 * 128 + c0];
        float2 x1 = make_float2(0.f, 0.f);
        if (has2) x1 = *(const float2*)&xl[(size_t)s1 * 128 + c0];

        // chain A <- edge i
        {
            float sx = xrv.x + x0.x;
            float sy = xrv.y + x0.y;
            sx = (sx > 0.f) ? sx : NEG_SLOPE * sx;
            sy = (sy > 0.f) ? sy : NEG_SLOPE * sy;
            float p = sx * av.x + sy * av.y;
            p += __shfl_xor(p, 1);
            p += __shfl_xor(p, 2);
            p += __shfl_xor(p, 4);
            float mn = fmaxf(mA, p);
            float sc = __expf(mA - mn);
            float w  = __expf(p - mn);
            lA = lA * sc + w;
            aA.x = aA.x * sc + w * x0.x;
            aA.y = aA.y * sc + w * x0.y;
            mA = mn;
        }
        // chain B <- edge i+1 (independent of chain A)
        if (has2) {
            float sx = xrv.x + x1.x;
            float sy = xrv.y + x1.y;
            sx = (sx > 0.f) ? sx : NEG_SLOPE * sx;
            sy = (sy > 0.f) ? sy : NEG_SLOPE * sy;
            float p = sx * av.x + sy * av.y;
            p += __shfl_xor(p, 1);
            p += __shfl_xor(p, 2);
            p += __shfl_xor(p, 4);
            float mn = fmaxf(mB, p);
            float sc = __expf(mB - mn);
            float w  = __expf(p - mn);
            lB = lB * sc + w;
            aB.x = aB.x * sc + w * x1.x;
            aB.y = aB.y * sc + w * x1.y;
            mB = mn;
        }
    }

    // exact merge of the two online-softmax states
    // (if a chain is empty: m=-3e38, l=0 -> exp(m-mn)=0 (or mn=m, l=0) -> no-op)
    float mn = fmaxf(mA, mB);
    float scA = __expf(mA - mn);
    float scB = __expf(mB - mn);
    float l = lA * scA + lB * scB;
    float2 acc = make_float2(aA.x * scA + aB.x * scB,
                             aA.y * scA + aB.y * scB);

    float inv = (l > 0.f) ? (1.f / l) : 0.f;
    float2 bv = *(const float2*)&bias[c0];
    float2 o = make_float2(acc.x * inv + bv.x, acc.y * inv + bv.y);
    *(float2*)&h[(size_t)node * 128 + c0] = o;
}

// ---------------- fused FFN (baseline, known-good): LN1 -> W1+SiLU -> W2 -> +res -> LN2
// block: 256 threads, 16 rows
__global__ __launch_bounds__(256) void k_ffn(const float* __restrict__ h,
        const float* __restrict__ g1, const float* __restrict__ bn1,
        const float* __restrict__ W1, const float* __restrict__ bW1,
        const float* __restrict__ W2, const float* __restrict__ bW2,
        const float* __restrict__ g2, const float* __restrict__ bn2,
        float* __restrict__ out, int N) {
    __shared__ __align__(16) float hs[16][128];
    __shared__ __align__(16) float ts[16][128];
    __shared__ __align__(16) float us[16][512];
    int tid = threadIdx.x;
    int row0 = blockIdx.x * 16;

    // load 16 rows of h
    for (int v = tid; v < 512; v += 256) {   // 512 float4
        int r = v >> 5, c4 = v & 31;
        int gr = row0 + r;
        float4 val = (gr < N) ? ((const float4*)h)[(size_t)gr * 32 + c4]
                              : make_float4(0.f, 0.f, 0.f, 0.f);
        *(float4*)&hs[r][c4 * 4] = val;
    }
    __syncthreads();

    // LN1: 16 groups of 16 lanes, one row each
    {
        int g = tid >> 4, l16 = tid & 15;
        int c = l16 * 8;
        float4 a = *(float4*)&hs[g][c];
        float4 b = *(float4*)&hs[g][c + 4];
        float sum = a.x + a.y + a.z + a.w + b.x + b.y + b.z + b.w;
        float sq  = a.x*a.x + a.y*a.y + a.z*a.z + a.w*a.w
                  + b.x*b.x + b.y*b.y + b.z*b.z + b.w*b.w;
#pragma unroll
        for (int msk = 1; msk < 16; msk <<= 1) {
            sum += __shfl_xor(sum, msk);
            sq  += __shfl_xor(sq,  msk);
        }
        float mu = sum * (1.f / 128.f);
        float var = sq * (1.f / 128.f) - mu * mu;
        float rstd = rsqrtf(var + LN_EPS);
#pragma unroll
        for (int u = 0; u < 8; ++u) {
            float xv = hs[g][c + u];
            ts[g][c + u] = (xv - mu) * rstd * g1[c + u] + bn1[c + u];
        }
    }
    __syncthreads();

    // GEMM1 + SiLU: ts[16][128] @ W1[128][512] -> us[16][512]
    {
        float acc0[16], acc1[16];
#pragma unroll
        for (int r = 0; r < 16; ++r) { acc0[r] = 0.f; acc1[r] = 0.f; }
        int j0 = tid, j1 = tid + 256;
        for (int k4 = 0; k4 < 32; ++k4) {
            int kb = k4 * 4;
            float wA0 = W1[(size_t)(kb + 0) * 512 + j0];
            float wA1 = W1[(size_t)(kb + 1) * 512 + j0];
            float wA2 = W1[(size_t)(kb + 2) * 512 + j0];
            float wA3 = W1[(size_t)(kb + 3) * 512 + j0];
            float wB0 = W1[(size_t)(kb + 0) * 512 + j1];
            float wB1 = W1[(size_t)(kb + 1) * 512 + j1];
            float wB2 = W1[(size_t)(kb + 2) * 512 + j1];
            float wB3 = W1[(size_t)(kb + 3) * 512 + j1];
#pragma unroll
            for (int r = 0; r < 16; ++r) {
                float4 tv = *(const float4*)&ts[r][kb];  // wave-uniform broadcast
                acc0[r] += tv.x * wA0 + tv.y * wA1 + tv.z * wA2 + tv.w * wA3;
                acc1[r] += tv.x * wB0 + tv.y * wB1 + tv.z * wB2 + tv.w * wB3;
            }
        }
        float b0 = bW1[j0], b1 = bW1[j1];
#pragma unroll
        for (int r = 0; r < 16; ++r) {
            float v0 = acc0[r] + b0;
            float v1 = acc1[r] + b1;
            us[r][j0] = v0 / (1.f + __expf(-v0));
            us[r][j1] = v1 / (1.f + __expf(-v1));
        }
    }
    __syncthreads();

    // GEMM2 + residual: us[16][512] @ W2[512][128] + bW2 + hs -> ts (reuse)
    {
        int j = tid & 127, rh = tid >> 7;  // rh: 0 -> rows 0..7, 1 -> rows 8..15
        float acc[8];
#pragma unroll
        for (int r = 0; r < 8; ++r) acc[r] = 0.f;
        for (int k4 = 0; k4 < 128; ++k4) {
            int kb = k4 * 4;
            float w0 = W2[(size_t)(kb + 0) * 128 + j];
            float w1 = W2[(size_t)(kb + 1) * 128 + j];
            float w2 = W2[(size_t)(kb + 2) * 128 + j];
            float w3 = W2[(size_t)(kb + 3) * 128 + j];
#pragma unroll
            for (int r = 0; r < 8; ++r) {
                float4 uv = *(const float4*)&us[rh * 8 + r][kb];
                acc[r] += uv.x * w0 + uv.y * w1 + uv.z * w2 + uv.w * w3;
            }
        }
        float bb = bW2[j];
#pragma unroll
        for (int r = 0; r < 8; ++r) {
            ts[rh * 8 + r][j] = acc[r] + bb + hs[rh * 8 + r][j];
        }
    }
    __syncthreads();

    // LN2 + store
    {
        int g = tid >> 4, l16 = tid & 15;
        int c = l16 * 8;
        float4 a = *(float4*)&ts[g][c];
        float4 b = *(float4*)&ts[g][c + 4];
        float sum = a.x + a.y + a.z + a.w + b.x + b.y + b.z + b.w;
        float sq  = a.x*a.x + a.y*a.y + a.z*a.z + a.w*a.w
                  + b.x*b.x + b.y*b.y + b.z*b.z + b.w*b.w;
#pragma unroll
        for (int msk = 1; msk < 16; msk <<= 1) {
            sum += __shfl_xor(sum, msk);
            sq  += __shfl_xor(sq,  msk);
        }
        float mu = sum * (1.f / 128.f);
        float var = sq * (1.f / 128.f) - mu * mu;
        float rstd = rsqrtf(var + LN_EPS);
        int gr = row0 + g;
        if (gr < N) {
#pragma unroll
            for (int u = 0; u < 8; ++u) {
                float xv = ts[g][c + u];
                out[(size_t)gr * 128 + c + u] =
                    (xv - mu) * rstd * g2[c + u] + bn2[c + u];
            }
        }
    }
}

// ---------------- launch ----------------
extern "C" void kernel_launch(void* const* d_in, const int* in_sizes, int n_in,
                              void* d_out, int out_size, void* d_ws, size_t ws_size,
                              hipStream_t stream) {
    const float* x        = (const float*)d_in[0];
    const int*   ei       = (const int*)  d_in[1];
    const float* Wl       = (const float*)d_in[2];
    const float* bl       = (const float*)d_in[3];
    const float* Wr       = (const float*)d_in[4];
    const float* br       = (const float*)d_in[5];
    const float* att      = (const float*)d_in[6];
    const float* bias_gat = (const float*)d_in[7];
    const float* g1       = (const float*)d_in[8];
    const float* bn1      = (const float*)d_in[9];
    const float* W1       = (const float*)d_in[10];
    const float* bW1      = (const float*)d_in[11];
    const float* W2       = (const float*)d_in[12];
    const float* bW2      = (const float*)d_in[13];
    const float* g2       = (const float*)d_in[14];
    const float* bn2      = (const float*)d_in[15];

    int N = in_sizes[0] / 128;   // B*N
    int E = in_sizes[1] / 2;

    char* w = (char*)d_ws;
    float* xl  = (float*)w; w += (size_t)N * 128 * 4;
    float* xr  = (float*)w; w += (size_t)N * 128 * 4;
    float* hb  = (float*)w; w += (size_t)N * 128 * 4;
    int* offs  = (int*)w;   w += (size_t)(N + 1) * 4;
    int* deg   = (int*)w;   w += (size_t)N * 4;
    int* csr   = (int*)w;   w += (size_t)E * 4;
    float* out = (float*)d_out;

    int eb = (E + 255) / 256;
    int nb = (N + 255) / 256;

    k_zero<<<nb, 256, 0, stream>>>(deg, N);
    k_deg<<<eb, 256, 0, stream>>>(ei, E, deg);
    k_scan<<<1, 1024, 0, stream>>>(deg, offs, N);
    k_zero<<<nb, 256, 0, stream>>>(deg, N);
    k_fill<<<eb, 256, 0, stream>>>(ei, E, offs, deg, csr);

    k_xlxr<<<(N + 31) / 32, 256, 0, stream>>>(x, Wl, bl, Wr, br, xl, xr, N);
    k_gat<<<(N + 3) / 4, 256, 0, stream>>>(xl, xr, att, bias_gat, offs, csr, hb, N);
    k_ffn<<<(N + 15) / 16, 256, 0, stream>>>(hb, g1, bn1, W1, bW1, W2, bW2,
                                             g2, bn2, out, N);
}

// Round 9
// 1211.739 us; speedup vs baseline: 1.0674x; 1.0222x over previous
//
#include <hip/hip_runtime.h>
#include <math.h>

#define FDIM 128
#define NEG_SLOPE 0.2f
#define LN_EPS 1e-5f

// ---------------- CSR build ----------------

__global__ void k_zero(int* __restrict__ p, int n) {
    int i = blockIdx.x * blockDim.x + threadIdx.x;
    if (i < n) p[i] = 0;
}

__global__ void k_deg(const int* __restrict__ ei, int E, int* __restrict__ deg) {
    int i = blockIdx.x * blockDim.x + threadIdx.x;
    if (i < E) atomicAdd(&deg[ei[E + i]], 1);
}

// single-block exclusive scan over N elements (N ~ 100k), 1024 threads
__global__ __launch_bounds__(1024) void k_scan(const int* __restrict__ deg,
                                               int* __restrict__ offs, int N) {
    __shared__ int tl[1024];
    int tid = threadIdx.x;
    int chunk = (N + 1023) >> 10;
    int s = tid * chunk;
    int e = s + chunk; if (e > N) e = N;
    int sum = 0;
    for (int i = s; i < e; ++i) sum += deg[i];
    tl[tid] = sum;
    __syncthreads();
    for (int off = 1; off < 1024; off <<= 1) {
        int v = (tid >= off) ? tl[tid - off] : 0;
        __syncthreads();
        tl[tid] += v;
        __syncthreads();
    }
    int run = tl[tid] - sum;  // exclusive prefix for this thread's chunk
    for (int i = s; i < e; ++i) { offs[i] = run; run += deg[i]; }
    if (tid == 1023) offs[N] = run;  // == E
}

__global__ void k_fill(const int* __restrict__ ei, int E, const int* __restrict__ offs,
                       int* __restrict__ cur, int* __restrict__ csr_src) {
    int i = blockIdx.x * blockDim.x + threadIdx.x;
    if (i < E) {
        int dst = ei[E + i];
        int p = offs[dst] + atomicAdd(&cur[dst], 1);
        csr_src[p] = ei[i];
    }
}

// ---------------- xl / xr linear transforms (baseline, known-good) ----------------
__global__ __launch_bounds__(256) void k_xlxr(const float* __restrict__ x,
        const float* __restrict__ Wl, const float* __restrict__ bl,
        const float* __restrict__ Wr, const float* __restrict__ br,
        float* __restrict__ xl, float* __restrict__ xr, int N) {
    __shared__ __align__(16) float xs[32][128];
    int tid = threadIdx.x;
    int row0 = blockIdx.x * 32;
    for (int v = tid; v < 32 * 32; v += 256) {   // 1024 float4
        int r = v >> 5, c4 = v & 31;
        int gr = row0 + r;
        float4 val = (gr < N) ? ((const float4*)x)[(size_t)gr * 32 + c4]
                              : make_float4(0.f, 0.f, 0.f, 0.f);
        *(float4*)&xs[r][c4 * 4] = val;
    }
    __syncthreads();

    int cg = tid & 63;   // 64 col groups of 4 -> 256 cols
    int rg = tid >> 6;   // 4 row groups of 8
    int j = cg * 4;
    const float* W = (j < 128) ? (Wl + j) : (Wr + (j - 128));
    const float* bp = (j < 128) ? (bl + j) : (br + (j - 128));
    float4 acc[8];
#pragma unroll
    for (int r = 0; r < 8; ++r) acc[r] = make_float4(0.f, 0.f, 0.f, 0.f);

    for (int k = 0; k < 128; ++k) {
        float4 w = *(const float4*)(W + (size_t)k * 128);
#pragma unroll
        for (int r = 0; r < 8; ++r) {
            float s = xs[rg * 8 + r][k];  // wave-uniform -> LDS broadcast
            acc[r].x += s * w.x; acc[r].y += s * w.y;
            acc[r].z += s * w.z; acc[r].w += s * w.w;
        }
    }
    float4 b = *(const float4*)bp;
    float* outb = (j < 128) ? xl : xr;
    int jj = (j < 128) ? j : (j - 128);
#pragma unroll
    for (int r = 0; r < 8; ++r) {
        int gr = row0 + rg * 8 + r;
        if (gr < N) {
            float4 v = make_float4(acc[r].x + b.x, acc[r].y + b.y,
                                   acc[r].z + b.z, acc[r].w + b.w);
            *(float4*)&outb[(size_t)gr * 128 + jj] = v;
        }
    }
}

// ---------------- GATv2 aggregation: one wave per node, online softmax ----------
// 4 independent online-softmax chains over edge residues mod 4 (exact merge at
// the end) + quad load issue for 4x memory-level parallelism. Arithmetic equals
// baseline up to associative softmax reordering.
#define GAT_UPD(m_, l_, a_, xv_) { \
    float sx_ = xrv.x + xv_.x; \
    float sy_ = xrv.y + xv_.y; \
    sx_ = (sx_ > 0.f) ? sx_ : NEG_SLOPE * sx_; \
    sy_ = (sy_ > 0.f) ? sy_ : NEG_SLOPE * sy_; \
    float p_ = sx_ * av.x + sy_ * av.y; \
    p_ += __shfl_xor(p_, 1); \
    p_ += __shfl_xor(p_, 2); \
    p_ += __shfl_xor(p_, 4); \
    float mn_ = fmaxf(m_, p_); \
    float sc_ = __expf(m_ - mn_); \
    float w_  = __expf(p_ - mn_); \
    l_ = l_ * sc_ + w_; \
    a_.x = a_.x * sc_ + w_ * xv_.x; \
    a_.y = a_.y * sc_ + w_ * xv_.y; \
    m_ = mn_; }

__global__ __launch_bounds__(256) void k_gat(const float* __restrict__ xl,
        const float* __restrict__ xr, const float* __restrict__ att,
        const float* __restrict__ bias,
        const int* __restrict__ offs, const int* __restrict__ csr_src,
        float* __restrict__ h, int N) {
    int wave = threadIdx.x >> 6;
    int lane = threadIdx.x & 63;
    int node = blockIdx.x * 4 + wave;
    if (node >= N) return;

    int c0 = lane * 2;  // channel pair; head = c0>>4, 8 lanes per head
    float2 xrv = *(const float2*)&xr[(size_t)node * 128 + c0];
    float2 av  = *(const float2*)&att[c0];

    float mA = -3.0e38f, lA = 0.f, mB = -3.0e38f, lB = 0.f;
    float mC = -3.0e38f, lC = 0.f, mD = -3.0e38f, lD = 0.f;
    float2 aA = make_float2(0.f, 0.f), aB = make_float2(0.f, 0.f);
    float2 aC = make_float2(0.f, 0.f), aD = make_float2(0.f, 0.f);

    int e0 = offs[node], e1 = offs[node + 1];
    int i = e0;
    for (; i + 3 < e1; i += 4) {
        // issue all four edge loads up-front (independent)
        int s0 = csr_src[i];
        int s1 = csr_src[i + 1];
        int s2 = csr_src[i + 2];
        int s3 = csr_src[i + 3];
        float2 x0 = *(const float2*)&xl[(size_t)s0 * 128 + c0];
        float2 x1 = *(const float2*)&xl[(size_t)s1 * 128 + c0];
        float2 x2 = *(const float2*)&xl[(size_t)s2 * 128 + c0];
        float2 x3 = *(const float2*)&xl[(size_t)s3 * 128 + c0];
        GAT_UPD(mA, lA, aA, x0);
        GAT_UPD(mB, lB, aB, x1);
        GAT_UPD(mC, lC, aC, x2);
        GAT_UPD(mD, lD, aD, x3);
    }
    for (; i < e1; ++i) {   // remainder (<=3 edges) -> chain A
        int s0 = csr_src[i];
        float2 x0 = *(const float2*)&xl[(size_t)s0 * 128 + c0];
        GAT_UPD(mA, lA, aA, x0);
    }

    // exact pairwise merges of the four online-softmax states
    // (empty chain: m=-3e38, l=0 -> its exp-scale is 0 or multiplies l=0 -> no-op)
    float mn1 = fmaxf(mA, mB);
    float sA = __expf(mA - mn1), sB = __expf(mB - mn1);
    float l1 = lA * sA + lB * sB;
    float2 a1 = make_float2(aA.x * sA + aB.x * sB, aA.y * sA + aB.y * sB);

    float mn2 = fmaxf(mC, mD);
    float sC = __expf(mC - mn2), sD = __expf(mD - mn2);
    float l2 = lC * sC + lD * sD;
    float2 a2 = make_float2(aC.x * sC + aD.x * sD, aC.y * sC + aD.y * sD);

    float mn = fmaxf(mn1, mn2);
    float s1m = __expf(mn1 - mn), s2m = __expf(mn2 - mn);
    float l = l1 * s1m + l2 * s2m;
    float2 acc = make_float2(a1.x * s1m + a2.x * s2m,
                             a1.y * s1m + a2.y * s2m);

    float inv = (l > 0.f) ? (1.f / l) : 0.f;
    float2 bv = *(const float2*)&bias[c0];
    float2 o = make_float2(acc.x * inv + bv.x, acc.y * inv + bv.y);
    *(float2*)&h[(size_t)node * 128 + c0] = o;
}

// ---------------- fused FFN (baseline + rcp-SiLU): LN1 -> W1+SiLU -> W2 -> +res -> LN2
// block: 256 threads, 16 rows
__global__ __launch_bounds__(256) void k_ffn(const float* __restrict__ h,
        const float* __restrict__ g1, const float* __restrict__ bn1,
        const float* __restrict__ W1, const float* __restrict__ bW1,
        const float* __restrict__ W2, const float* __restrict__ bW2,
        const float* __restrict__ g2, const float* __restrict__ bn2,
        float* __restrict__ out, int N) {
    __shared__ __align__(16) float hs[16][128];
    __shared__ __align__(16) float ts[16][128];
    __shared__ __align__(16) float us[16][512];
    int tid = threadIdx.x;
    int row0 = blockIdx.x * 16;

    // load 16 rows of h
    for (int v = tid; v < 512; v += 256) {   // 512 float4
        int r = v >> 5, c4 = v & 31;
        int gr = row0 + r;
        float4 val = (gr < N) ? ((const float4*)h)[(size_t)gr * 32 + c4]
                              : make_float4(0.f, 0.f, 0.f, 0.f);
        *(float4*)&hs[r][c4 * 4] = val;
    }
    __syncthreads();

    // LN1: 16 groups of 16 lanes, one row each
    {
        int g = tid >> 4, l16 = tid & 15;
        int c = l16 * 8;
        float4 a = *(float4*)&hs[g][c];
        float4 b = *(float4*)&hs[g][c + 4];
        float sum = a.x + a.y + a.z + a.w + b.x + b.y + b.z + b.w;
        float sq  = a.x*a.x + a.y*a.y + a.z*a.z + a.w*a.w
                  + b.x*b.x + b.y*b.y + b.z*b.z + b.w*b.w;
#pragma unroll
        for (int msk = 1; msk < 16; msk <<= 1) {
            sum += __shfl_xor(sum, msk);
            sq  += __shfl_xor(sq,  msk);
        }
        float mu = sum * (1.f / 128.f);
        float var = sq * (1.f / 128.f) - mu * mu;
        float rstd = rsqrtf(var + LN_EPS);
#pragma unroll
        for (int u = 0; u < 8; ++u) {
            float xv = hs[g][c + u];
            ts[g][c + u] = (xv - mu) * rstd * g1[c + u] + bn1[c + u];
        }
    }
    __syncthreads();

    // GEMM1 + SiLU: ts[16][128] @ W1[128][512] -> us[16][512]
    {
        float acc0[16], acc1[16];
#pragma unroll
        for (int r = 0; r < 16; ++r) { acc0[r] = 0.f; acc1[r] = 0.f; }
        int j0 = tid, j1 = tid + 256;
        for (int k4 = 0; k4 < 32; ++k4) {
            int kb = k4 * 4;
            float wA0 = W1[(size_t)(kb + 0) * 512 + j0];
            float wA1 = W1[(size_t)(kb + 1) * 512 + j0];
            float wA2 = W1[(size_t)(kb + 2) * 512 + j0];
            float wA3 = W1[(size_t)(kb + 3) * 512 + j0];
            float wB0 = W1[(size_t)(kb + 0) * 512 + j1];
            float wB1 = W1[(size_t)(kb + 1) * 512 + j1];
            float wB2 = W1[(size_t)(kb + 2) * 512 + j1];
            float wB3 = W1[(size_t)(kb + 3) * 512 + j1];
#pragma unroll
            for (int r = 0; r < 16; ++r) {
                float4 tv = *(const float4*)&ts[r][kb];  // wave-uniform broadcast
                acc0[r] += tv.x * wA0 + tv.y * wA1 + tv.z * wA2 + tv.w * wA3;
                acc1[r] += tv.x * wB0 + tv.y * wB1 + tv.z * wB2 + tv.w * wB3;
            }
        }
        float b0 = bW1[j0], b1 = bW1[j1];
#pragma unroll
        for (int r = 0; r < 16; ++r) {
            float v0 = acc0[r] + b0;
            float v1 = acc1[r] + b1;
            // SiLU via v_rcp_f32 (denominator in [1, 2.72+]; ~1 ulp approx)
            us[r][j0] = v0 * __builtin_amdgcn_rcpf(1.f + __expf(-v0));
            us[r][j1] = v1 * __builtin_amdgcn_rcpf(1.f + __expf(-v1));
        }
    }
    __syncthreads();

    // GEMM2 + residual: us[16][512] @ W2[512][128] + bW2 + hs -> ts (reuse)
    {
        int j = tid & 127, rh = tid >> 7;  // rh: 0 -> rows 0..7, 1 -> rows 8..15
        float acc[8];
#pragma unroll
        for (int r = 0; r < 8; ++r) acc[r] = 0.f;
        for (int k4 = 0; k4 < 128; ++k4) {
            int kb = k4 * 4;
            float w0 = W2[(size_t)(kb + 0) * 128 + j];
            float w1 = W2[(size_t)(kb + 1) * 128 + j];
            float w2 = W2[(size_t)(kb + 2) * 128 + j];
            float w3 = W2[(size_t)(kb + 3) * 128 + j];
#pragma unroll
            for (int r = 0; r < 8; ++r) {
                float4 uv = *(const float4*)&us[rh * 8 + r][kb];
                acc[r] += uv.x * w0 + uv.y * w1 + uv.z * w2 + uv.w * w3;
            }
        }
        float bb = bW2[j];
#pragma unroll
        for (int r = 0; r < 8; ++r) {
            ts[rh * 8 + r][j] = acc[r] + bb + hs[rh * 8 + r][j];
        }
    }
    __syncthreads();

    // LN2 + store
    {
        int g = tid >> 4, l16 = tid & 15;
        int c = l16 * 8;
        float4 a = *(float4*)&ts[g][c];
        float4 b = *(float4*)&ts[g][c + 4];
        float sum = a.x + a.y + a.z + a.w + b.x + b.y + b.z + b.w;
        float sq  = a.x*a.x + a.y*a.y + a.z*a.z + a.w*a.w
                  + b.x*b.x + b.y*b.y + b.z*b.z + b.w*b.w;
#pragma unroll
        for (int msk = 1; msk < 16; msk <<= 1) {
            sum += __shfl_xor(sum, msk);
            sq  += __shfl_xor(sq,  msk);
        }
        float mu = sum * (1.f / 128.f);
        float var = sq * (1.f / 128.f) - mu * mu;
        float rstd = rsqrtf(var + LN_EPS);
        int gr = row0 + g;
        if (gr < N) {
#pragma unroll
            for (int u = 0; u < 8; ++u) {
                float xv = ts[g][c + u];
                out[(size_t)gr * 128 + c + u] =
                    (xv - mu) * rstd * g2[c + u] + bn2[c + u];
            }
        }
    }
}

// ---------------- launch ----------------
extern "C" void kernel_launch(void* const* d_in, const int* in_sizes, int n_in,
                              void* d_out, int out_size, void* d_ws, size_t ws_size,
                              hipStream_t stream) {
    const float* x        = (const float*)d_in[0];
    const int*   ei       = (const int*)  d_in[1];
    const float* Wl       = (const float*)d_in[2];
    const float* bl       = (const float*)d_in[3];
    const float* Wr       = (const float*)d_in[4];
    const float* br       = (const float*)d_in[5];
    const float* att      = (const float*)d_in[6];
    const float* bias_gat = (const float*)d_in[7];
    const float* g1       = (const float*)d_in[8];
    const float* bn1      = (const float*)d_in[9];
    const float* W1       = (const float*)d_in[10];
    const float* bW1      = (const float*)d_in[11];
    const float* W2       = (const float*)d_in[12];
    const float* bW2      = (const float*)d_in[13];
    const float* g2       = (const float*)d_in[14];
    const float* bn2      = (const float*)d_in[15];

    int N = in_sizes[0] / 128;   // B*N
    int E = in_sizes[1] / 2;

    char* w = (char*)d_ws;
    float* xl  = (float*)w; w += (size_t)N * 128 * 4;
    float* xr  = (float*)w; w += (size_t)N * 128 * 4;
    float* hb  = (float*)w; w += (size_t)N * 128 * 4;
    int* offs  = (int*)w;   w += (size_t)(N + 1) * 4;
    int* deg   = (int*)w;   w += (size_t)N * 4;
    int* csr   = (int*)w;   w += (size_t)E * 4;
    float* out = (float*)d_out;

    int eb = (E + 255) / 256;
    int nb = (N + 255) / 256;

    k_zero<<<nb, 256, 0, stream>>>(deg, N);
    k_deg<<<eb, 256, 0, stream>>>(ei, E, deg);
    k_scan<<<1, 1024, 0, stream>>>(deg, offs, N);
    k_zero<<<nb, 256, 0, stream>>>(deg, N);
    k_fill<<<eb, 256, 0, stream>>>(ei, E, offs, deg, csr);

    k_xlxr<<<(N + 31) / 32, 256, 0, stream>>>(x, Wl, bl, Wr, br, xl, xr, N);
    k_gat<<<(N + 3) / 4, 256, 0, stream>>>(xl, xr, att, bias_gat, offs, csr, hb, N);
    k_ffn<<<(N + 15) / 16, 256, 0, stream>>>(hb, g1, bn1, W1, bW1, W2, bW2,
                                             g2, bn2, out, N);
}